// Round 1
// baseline (30.741 us; speedup 1.0000x reference)
//
#include <hip/hip_runtime.h>
#include <math.h>

// Problem constants (from reference): C=8, V=12, D=64, B=32768
#define NC 8
#define NV 12
#define ND 64
#define NB 32768
#define NROWS (NC * NV)     // 96 table rows
#define RS 132              // padded LDS row stride in floats (128 data + 4 pad)

// Output layout (flat f32): [0..65535] inferences [B,2], [65536] weighted_loss,
// [65537..98304] pairwise [B,1]
#define OUT_LOSS 65536
#define OUT_PW   65537

__global__ __launch_bounds__(256, 2) void fm_kernel(
    const int*   __restrict__ idx,    // [C,B]
    const float* __restrict__ label,  // [B,2]
    const float* __restrict__ posw,   // [B,2]
    const float* __restrict__ meant,  // [C,V,D]
    const float* __restrict__ stdt,   // [C,V,D]
    const float* __restrict__ act,    // [2,D]
    const float* __restrict__ noise,  // [B*D]
    float*       __restrict__ out)
{
    __shared__ float tab[NROWS * RS];   // interleaved {mu, softplus(std)*0.01}
    __shared__ float lossbuf[8];

    const int tid = threadIdx.x;

    // ---- stage tables into LDS, fusing softplus * 0.01 ----
    for (int i = tid; i < NROWS * ND; i += 256) {
        const int r = i >> 6;         // row = c*12+g
        const int d = i & 63;
        const float mu = meant[i];
        const float x  = stdt[i];
        // stable softplus: log1p(exp(x)) = max(x,0) + log1p(exp(-|x|))
        const float sp = fmaxf(x, 0.0f) + log1pf(expf(-fabsf(x)));
        tab[r * RS + 2 * d]     = mu;
        tab[r * RS + 2 * d + 1] = sp * 0.01f;
    }
    __syncthreads();

    const int lane = tid & 63;
    const int m    = lane & 31;   // position within half-wave
    const int h    = lane >> 5;   // which b of the pair
    const int wave = tid >> 6;
    const int gw   = blockIdx.x * 4 + wave;   // global wave id, 0..2047

    // action_table fragments for this lane's two d's (d0=2m, d1=2m+1)
    const float2 a0 = *(const float2*)(act + 2 * m);        // action row 0
    const float2 a1 = *(const float2*)(act + ND + 2 * m);   // action row 1

    float lossacc = 0.0f;

    // Each wave handles 8 consecutive b-pairs: B = 512 blk * 4 waves * 2 b * 8 it
    for (int it = 0; it < 8; ++it) {
        const int p = gw * 8 + it;       // pair index 0..16383
        const int b = 2 * p + h;         // this half's b

        // noise for this lane's two d's (coalesced: 512B contiguous per wave)
        const float2 v = *(const float2*)(noise + b * ND + 2 * m);

        float s0 = 0.0f, s1 = 0.0f, esq = 0.0f;
        #pragma unroll
        for (int c = 0; c < NC; ++c) {
            const int g = idx[c * NB + b];                       // wave-half-uniform
            const float4 t = *(const float4*)(&tab[(c * NV + g) * RS + 4 * m]);
            const float e0 = fmaf(t.y, v.x, t.x);                // mu + sp01*v
            const float e1 = fmaf(t.w, v.y, t.z);
            s0 += e0;
            s1 += e1;
            esq = fmaf(e0, e0, fmaf(e1, e1, esq));
        }

        // 4 partial scalars for this b, reduce across the 32-lane half
        float r0 = fmaf(s0, s0, s1 * s1);       // ||s||^2 partial
        float r1 = esq;                          // sum e^2 partial
        float r2 = fmaf(a0.x, s0, a0.y * s1);    // inf0 partial
        float r3 = fmaf(a1.x, s0, a1.y * s1);    // inf1 partial
        #pragma unroll
        for (int off = 1; off <= 16; off <<= 1) {
            r0 += __shfl_xor(r0, off, 64);
            r1 += __shfl_xor(r1, off, 64);
            r2 += __shfl_xor(r2, off, 64);
            r3 += __shfl_xor(r3, off, 64);
        }

        if (m == 0) {
            const float2 lb = *(const float2*)(label + 2 * b);
            const float2 pw = *(const float2*)(posw + 2 * b);
            ((float2*)out)[b] = make_float2(r2, r3);       // inferences
            out[OUT_PW + b]   = 0.5f * (r0 - r1);          // pairwise
            const float d0 = r2 - lb.x;
            const float d1 = r3 - lb.y;
            lossacc += pw.x * d0 * d0 + pw.y * d1 * d1;
        }
    }

    // ---- block-level loss reduction, one atomic per block ----
    if (m == 0) lossbuf[wave * 2 + h] = lossacc;
    __syncthreads();
    if (tid == 0) {
        float s = 0.0f;
        #pragma unroll
        for (int i = 0; i < 8; ++i) s += lossbuf[i];
        atomicAdd(out + OUT_LOSS, s * (1.0f / (float)NB));
    }
}

extern "C" void kernel_launch(void* const* d_in, const int* in_sizes, int n_in,
                              void* d_out, int out_size, void* d_ws, size_t ws_size,
                              hipStream_t stream) {
    const int*   idx   = (const int*)d_in[0];
    const float* label = (const float*)d_in[1];
    const float* posw  = (const float*)d_in[2];
    const float* meant = (const float*)d_in[3];
    const float* stdt  = (const float*)d_in[4];
    const float* act   = (const float*)d_in[5];
    const float* noise = (const float*)d_in[6];
    float* out = (float*)d_out;

    // zero the loss accumulator (graph-capturable memset node)
    hipMemsetAsync(out + OUT_LOSS, 0, sizeof(float), stream);
    fm_kernel<<<512, 256, 0, stream>>>(idx, label, posw, meant, stdt, act, noise, out);
}

// Round 2
// 16.519 us; speedup vs baseline: 1.8610x; 1.8610x over previous
//
#include <hip/hip_runtime.h>
#include <math.h>

// C=8, V=12, D=64, B=32768
#define NC 8
#define NV 12
#define ND 64
#define NB 32768
#define NROWS 96            // C*V table rows
#define RSW 68              // LDS row stride in 32-bit words (64 data + 4 pad; 272B, 16B-aligned)
#define OUT_LOSS 65536
#define OUT_PW   65537

__device__ __forceinline__ unsigned bf16rne(float x) {
    const unsigned u = __float_as_uint(x);
    return (u + 0x7FFFu + ((u >> 16) & 1u)) >> 16;
}

// ---- main kernel: 256 blocks x 512 threads; each wave handles 16 b's ----
__global__ __launch_bounds__(512, 2) void fm_main(
    const int*   __restrict__ idx,    // [C,B]
    const float* __restrict__ label,  // [B,2]
    const float* __restrict__ posw,   // [B,2]
    const float* __restrict__ meant,  // [C,V,D]
    const float* __restrict__ stdt,   // [C,V,D]
    const float* __restrict__ act,    // [2,D]
    const float* __restrict__ noise,  // [B*D]
    float*       __restrict__ out,
    float*       __restrict__ partial)
{
    __shared__ unsigned tab[NROWS * RSW];  // word = bf16(mu) | bf16(softplus*0.01)<<16
    __shared__ float wloss[8];

    const int tid = threadIdx.x;

    // stage table: 6144 elements, float4-vectorized, fuse softplus*0.01, pack bf16
    for (int i = tid * 4; i < NROWS * ND; i += 512 * 4) {
        const float4 mu4 = *(const float4*)(meant + i);
        const float4 sd4 = *(const float4*)(stdt + i);
        const int r = i >> 6, d = i & 63;
        uint4 w;
        {
            const float x = sd4.x, sp = fmaxf(x,0.f)+log1pf(expf(-fabsf(x)));
            w.x = bf16rne(mu4.x) | (bf16rne(sp*0.01f) << 16);
        }{
            const float x = sd4.y, sp = fmaxf(x,0.f)+log1pf(expf(-fabsf(x)));
            w.y = bf16rne(mu4.y) | (bf16rne(sp*0.01f) << 16);
        }{
            const float x = sd4.z, sp = fmaxf(x,0.f)+log1pf(expf(-fabsf(x)));
            w.z = bf16rne(mu4.z) | (bf16rne(sp*0.01f) << 16);
        }{
            const float x = sd4.w, sp = fmaxf(x,0.f)+log1pf(expf(-fabsf(x)));
            w.w = bf16rne(mu4.w) | (bf16rne(sp*0.01f) << 16);
        }
        *(uint4*)(&tab[r * RSW + d]) = w;
    }
    __syncthreads();

    const int lane = tid & 63;
    const int wave = tid >> 6;
    const int m    = lane & 7;    // d-octet: owns d = 8m..8m+7
    const int bsub = lane >> 3;   // which of the wave's 8 concurrent b's
    const int gw   = blockIdx.x * 8 + wave;   // 0..2047

    const float4 a0l = *(const float4*)(act + 8*m);
    const float4 a0h = *(const float4*)(act + 8*m + 4);
    const float4 a1l = *(const float4*)(act + ND + 8*m);
    const float4 a1h = *(const float4*)(act + ND + 8*m + 4);

    float lossacc = 0.f;

    #pragma unroll
    for (int it = 0; it < 2; ++it) {
        const int b = gw * 16 + it * 8 + bsub;
        const float4 vl = *(const float4*)(noise + b * ND + 8*m);
        const float4 vh = *(const float4*)(noise + b * ND + 8*m + 4);

        float s0=0,s1=0,s2=0,s3=0,s4=0,s5=0,s6=0,s7=0;
        float esq = 0.f;

        #pragma unroll
        for (int c = 0; c < NC; ++c) {
            const int g = idx[c * NB + b];                  // uniform across the 8-lane group
            const unsigned* rp = &tab[(c * NV + g) * RSW + 8*m];
            const uint4 w0 = *(const uint4*)(rp);
            const uint4 w1 = *(const uint4*)(rp + 4);
#define EMB(W, VV, SS) { \
            const float mu_ = __uint_as_float((W) << 16); \
            const float sp_ = __uint_as_float((W) & 0xFFFF0000u); \
            const float e_  = fmaf(sp_, (VV), mu_); \
            SS += e_; esq = fmaf(e_, e_, esq); }
            EMB(w0.x, vl.x, s0) EMB(w0.y, vl.y, s1) EMB(w0.z, vl.z, s2) EMB(w0.w, vl.w, s3)
            EMB(w1.x, vh.x, s4) EMB(w1.y, vh.y, s5) EMB(w1.z, vh.z, s6) EMB(w1.w, vh.w, s7)
#undef EMB
        }

        // 4 partials for this b's d-octet
        float r0 = s0*s0+s1*s1+s2*s2+s3*s3+s4*s4+s5*s5+s6*s6+s7*s7;  // ||s||^2 part
        float r1 = esq;                                              // sum e^2 part
        float r2 = s0*a0l.x+s1*a0l.y+s2*a0l.z+s3*a0l.w+s4*a0h.x+s5*a0h.y+s6*a0h.z+s7*a0h.w;
        float r3 = s0*a1l.x+s1*a1l.y+s2*a1l.z+s3*a1l.w+s4*a1h.x+s5*a1h.y+s6*a1h.z+s7*a1h.w;

        // reduce across the 8-lane group (masks stay within low 3 lane bits)
        #pragma unroll
        for (int off = 1; off <= 4; off <<= 1) {
            r0 += __shfl_xor(r0, off, 64);
            r1 += __shfl_xor(r1, off, 64);
            r2 += __shfl_xor(r2, off, 64);
            r3 += __shfl_xor(r3, off, 64);
        }

        if (m == 0) {
            const float2 lb = *(const float2*)(label + 2*b);
            const float2 pw = *(const float2*)(posw + 2*b);
            ((float2*)out)[b] = make_float2(r2, r3);
            out[OUT_PW + b]   = 0.5f * (r0 - r1);
            const float d0 = r2 - lb.x, d1 = r3 - lb.y;
            lossacc += pw.x*d0*d0 + pw.y*d1*d1;
        }
    }

    // loss: only m==0 lanes hold values; zero others then reduce across bsub bits
    if (m != 0) lossacc = 0.f;
    #pragma unroll
    for (int off = 8; off <= 32; off <<= 1) lossacc += __shfl_xor(lossacc, off, 64);
    if (lane == 0) wloss[wave] = lossacc;
    __syncthreads();
    if (tid == 0) {
        float s = 0.f;
        #pragma unroll
        for (int i = 0; i < 8; ++i) s += wloss[i];
        partial[blockIdx.x] = s;
    }
}

// ---- tiny reduce: 256 block partials -> loss scalar ----
__global__ __launch_bounds__(256) void fm_loss(const float* __restrict__ partial,
                                               float* __restrict__ out) {
    const int tid = threadIdx.x;
    float v = partial[tid];
    #pragma unroll
    for (int off = 1; off <= 32; off <<= 1) v += __shfl_xor(v, off, 64);
    __shared__ float ws[4];
    if ((tid & 63) == 0) ws[tid >> 6] = v;
    __syncthreads();
    if (tid == 0) out[OUT_LOSS] = (ws[0]+ws[1]+ws[2]+ws[3]) * (1.0f/(float)NB);
}

extern "C" void kernel_launch(void* const* d_in, const int* in_sizes, int n_in,
                              void* d_out, int out_size, void* d_ws, size_t ws_size,
                              hipStream_t stream) {
    const int*   idx   = (const int*)d_in[0];
    const float* label = (const float*)d_in[1];
    const float* posw  = (const float*)d_in[2];
    const float* meant = (const float*)d_in[3];
    const float* stdt  = (const float*)d_in[4];
    const float* act   = (const float*)d_in[5];
    const float* noise = (const float*)d_in[6];
    float* out = (float*)d_out;
    float* partial = (float*)d_ws;   // 256 floats, fully written each call

    fm_main<<<256, 512, 0, stream>>>(idx, label, posw, meant, stdt, act, noise, out, partial);
    fm_loss<<<1, 256, 0, stream>>>(partial, out);
}